// Round 13
// baseline (169.778 us; speedup 1.0000x reference)
//
#include <hip/hip_runtime.h>

// MaxUnpooling2D scatter-add, round 13: two-phase binning, zero global atomics.
// vs R12 (144.9us = K1 39 + K2 106): K2 blocks halved (TPB2=256, REGION 16KB,
// NBIN 1024) -> 8 independent blocks/CU at 32 waves/CU for phase overlap
// (R10 showed K2 is wave-count-sensitive). Records now local12|f20 (more
// precision). K1 scan: 2-bins/thread wave-shuffle, 3 barriers (was 18).
//
// dest(in-batch, 22b) = (m & ~255) | c, m = y<<15|x<<8|f (Ho=Wo=128, C=256).
// region r = dest>>12 (1024/batch x 4096 floats = 16 KB).
// record = (dest & 4095) << 20 | (f32bits + 0x800) >> 12   (20-bit float).

typedef float __attribute__((ext_vector_type(4))) f32x4;
typedef int   __attribute__((ext_vector_type(4))) i32x4;
typedef unsigned int u32;
typedef u32 __attribute__((ext_vector_type(2))) u32x2;
typedef u32 __attribute__((ext_vector_type(4))) u32x4;

constexpr int NIN    = 16 * 64 * 64 * 256;  // 2^24 elements
constexpr int NBIN   = 1024;                // regions per batch
constexpr int REGION = 4096;                // floats per region (16 KB)
constexpr int RPB    = 16384;               // records per K1 block
constexpr int NBLK1  = NIN / RPB;           // 1024
constexpr int TPB1   = 512;
constexpr int SRCB   = (1 << 20) / RPB;     // 64 source blocks per batch
constexpr int TPB2   = 256;
constexpr int NBLK2  = 16 * NBIN;           // 16384

// ---------------- K1: single-pass block-local counting sort ----------------
__global__ __launch_bounds__(TPB1, 4) void bin_sort(
    const f32x4* __restrict__ upd, const i32x4* __restrict__ msk,
    u32* __restrict__ recs, u32* __restrict__ packed)
{
    __shared__ int hist[NBIN];              // 4 KB
    __shared__ int cursor[NBIN];            // 4 KB
    __shared__ int wavesum[8];
    __shared__ u32 staged[RPB];             // 64 KB

    const int tid  = threadIdx.x;
    const int lane = tid & 63;
    const int wv   = tid >> 6;              // 0..7
    const int blk  = blockIdx.x;
    const int v0   = blk * (RPB / 4);

    hist[tid] = 0; hist[tid + TPB1] = 0;
    __syncthreads();

    // load once (NT), pack into registers, histogram
    u32 pk[32]; int bin[32];
#pragma unroll
    for (int j = 0; j < 8; ++j) {
        const int t = v0 + tid + j * TPB1;
        i32x4 m = __builtin_nontemporal_load(&msk[t]);
        f32x4 u = __builtin_nontemporal_load(&upd[t]);
        const int c = (t << 2) & 255;
        {
            const u32 d = (u32)((m.x & ~255) | c);
            bin[j*4+0] = (int)(d >> 12);
            pk[j*4+0] = ((d & 4095) << 20) | ((__float_as_uint(u.x) + 0x800) >> 12);
        }
        {
            const u32 d = (u32)((m.y & ~255) | (c + 1));
            bin[j*4+1] = (int)(d >> 12);
            pk[j*4+1] = ((d & 4095) << 20) | ((__float_as_uint(u.y) + 0x800) >> 12);
        }
        {
            const u32 d = (u32)((m.z & ~255) | (c + 2));
            bin[j*4+2] = (int)(d >> 12);
            pk[j*4+2] = ((d & 4095) << 20) | ((__float_as_uint(u.z) + 0x800) >> 12);
        }
        {
            const u32 d = (u32)((m.w & ~255) | (c + 3));
            bin[j*4+3] = (int)(d >> 12);
            pk[j*4+3] = ((d & 4095) << 20) | ((__float_as_uint(u.w) + 0x800) >> 12);
        }
#pragma unroll
        for (int e = 0; e < 4; ++e)
            atomicAdd(&hist[bin[j*4+e]], 1);
    }
    __syncthreads();

    // exclusive prefix over 1024 bins: 2 bins/thread, wave shuffle scan
    const int i0 = 2 * tid, i1 = i0 + 1;
    const int h0 = hist[i0], h1 = hist[i1];
    int s = h0 + h1;
#pragma unroll
    for (int d = 1; d < 64; d <<= 1) {
        const int v = __shfl_up(s, d, 64);
        if (lane >= d) s += v;
    }
    if (lane == 63) wavesum[wv] = s;
    __syncthreads();
    int woff = 0;
    for (int k = 0; k < wv; ++k) woff += wavesum[k];
    const int e0 = woff + s - h0 - h1;
    const int e1 = e0 + h0;
    cursor[i0] = e0;
    cursor[i1] = e1;
    // block-major table [blk][bin], 8 B per thread, coalesced
    *(u32x2*)&packed[(size_t)blk * NBIN + i0] =
        u32x2{((u32)e0 << 16) | (u32)h0, ((u32)e1 << 16) | (u32)h1};
    __syncthreads();

    // scatter from registers into staged, sorted by region
#pragma unroll
    for (int k = 0; k < 32; ++k)
        staged[atomicAdd(&cursor[bin[k]], 1)] = pk[k];
    __syncthreads();

    // coalesced copy staged -> global segment (blk * 64 KB)
    u32x4* sg = (u32x4*)staged;
    u32x4* gg = (u32x4*)(recs + (size_t)blk * RPB);
#pragma unroll
    for (int j = 0; j < RPB / 4 / TPB1; ++j)
        gg[tid + j * TPB1] = sg[tid + j * TPB1];
}

// ---------------- K2: wave-per-chunk gather + LDS accumulate ----------------
__global__ __launch_bounds__(TPB2, 8) void accumulate(
    const u32* __restrict__ recs, const u32* __restrict__ packed,
    float* __restrict__ out)
{
    __shared__ float region[REGION];        // 16 KB

    const int tid  = threadIdx.x;
    const int lane = tid & 63;
    const int wv   = tid >> 6;              // 0..3
    // XCD-bijective swizzle: consecutive logical regions share an XCD L2.
    const int lid = ((blockIdx.x & 7) << 11) | (blockIdx.x >> 3);
    const int b = lid >> 10;                // batch
    const int r = lid & (NBIN - 1);         // region

    f32x4* rv = (f32x4*)region;
#pragma unroll
    for (int j = 0; j < REGION / 4 / TPB2; ++j)
        rv[tid + j * TPB2] = f32x4{0.f, 0.f, 0.f, 0.f};

    // lane reads packed (off,cnt) of chunk `lane` for this region
    const u32 pl = packed[(size_t)(b * SRCB + lane) * NBIN + r];
    __syncthreads();                        // region zeroed before atomics

    // wave wv owns chunks wv*16 .. wv*16+15: 16 independent coalesced loads
    u32 rec[16];
#pragma unroll
    for (int j = 0; j < 16; ++j) {
        const int k = (wv << 4) | j;
        const u32 pj = __shfl(pl, k, 64);
        const int cnt = (int)(pj & 0xFFFF);
        const u32 idx = (u32)((b * SRCB + k) * RPB) + (pj >> 16);
        rec[j] = recs[idx + (lane < cnt ? lane : 0)];   // safe overread
    }
#pragma unroll
    for (int j = 0; j < 16; ++j) {
        const int k = (wv << 4) | j;
        const u32 pj = __shfl(pl, k, 64);
        if (lane < (int)(pj & 0xFFFF))
            atomicAdd(&region[rec[j] >> 20],
                      __uint_as_float((rec[j] & 0xFFFFF) << 12));
    }
    // rare tails (cnt > 64): statistically never executes (mean 16)
#pragma unroll
    for (int j = 0; j < 16; ++j) {
        const int k = (wv << 4) | j;
        const u32 pj = __shfl(pl, k, 64);
        const int cnt = (int)(pj & 0xFFFF);
        const u32 idx = (u32)((b * SRCB + k) * RPB) + (pj >> 16);
        for (int i = 64 + lane; i < cnt; i += 64) {
            const u32 p = recs[idx + i];
            atomicAdd(&region[p >> 20], __uint_as_float((p & 0xFFFFF) << 12));
        }
    }
    __syncthreads();

    // nontemporal write-out: output never re-read; keep L2/L3 for the gather
    f32x4* og = (f32x4*)(out + ((size_t)b << 22) + ((size_t)r << 12));
#pragma unroll
    for (int j = 0; j < REGION / 4 / TPB2; ++j)
        __builtin_nontemporal_store(rv[tid + j * TPB2], &og[tid + j * TPB2]);
}

// ---------------- fallback (ws too small): R1 atomic scatter ----------------
__global__ __launch_bounds__(256) void unpool_scatter(
    const f32x4* __restrict__ upd, const i32x4* __restrict__ msk,
    float* __restrict__ out)
{
    const int t = blockIdx.x * 256 + threadIdx.x;
    const int e = t << 2;
    f32x4 u = upd[t];
    i32x4 m = msk[t];
    const int b = e >> 20;
    const int c = e & 255;
    float* ob = out + ((long long)b << 22);
    atomicAdd(ob + ((m.x & ~255) | (c    )), u.x);
    atomicAdd(ob + ((m.y & ~255) | (c + 1)), u.y);
    atomicAdd(ob + ((m.z & ~255) | (c + 2)), u.z);
    atomicAdd(ob + ((m.w & ~255) | (c + 3)), u.w);
}

extern "C" void kernel_launch(void* const* d_in, const int* in_sizes, int n_in,
                              void* d_out, int out_size, void* d_ws, size_t ws_size,
                              hipStream_t stream) {
    const f32x4* upd = (const f32x4*)d_in[0];
    const i32x4* msk = (const i32x4*)d_in[1];
    float* out = (float*)d_out;

    constexpr size_t REC_BYTES = (size_t)NIN * 4;                    // 64 MiB
    constexpr size_t PCK_BYTES = (size_t)NBLK1 * NBIN * sizeof(u32); // 4 MiB

    if (ws_size >= REC_BYTES + PCK_BYTES + 4) {      // +4: guarded overread
        u32* recs = (u32*)d_ws;
        u32* packed = (u32*)((char*)d_ws + REC_BYTES);
        bin_sort<<<NBLK1, TPB1, 0, stream>>>(upd, msk, recs, packed);
        accumulate<<<NBLK2, TPB2, 0, stream>>>(recs, packed, out);
    } else {
        (void)hipMemsetAsync(out, 0, (size_t)out_size * sizeof(float), stream);
        unpool_scatter<<<NIN / 4 / 256, 256, 0, stream>>>(upd, msk, out);
    }
}

// Round 14
// 148.797 us; speedup vs baseline: 1.1410x; 1.1410x over previous
//
#include <hip/hip_runtime.h>

// MaxUnpooling2D scatter-add, round 14: two-phase binning, zero global atomics.
// vs R12 (best, 144.9 = K1 39 + K2 106): K2 processes 4 CONSECUTIVE regions
// per block (grid 2048), software-pipelined: region i+1's table+gather loads
// issue during region i's atomics/writeout -> serial table->gather->atomic
// chain hidden; consecutive regions' chunks are contiguous in recs (L2 reuse).
// K1: wave-shuffle scan (2 barriers, was 18). Config stays R12's optimum
// (NBIN=512, REGION 32KB, TPB2=512).
//
// dest(in-batch, 22b) = (m & ~255) | c, m = y<<15|x<<8|f (Ho=Wo=128, C=256).
// region r = dest>>13 = m>>13 (512/batch x 8192 floats = 32 KB).
// record = (dest & 8191) << 19 | (f32bits + 0x1000) >> 13   (19-bit float).

typedef float __attribute__((ext_vector_type(4))) f32x4;
typedef int   __attribute__((ext_vector_type(4))) i32x4;
typedef unsigned int u32;
typedef u32 __attribute__((ext_vector_type(4))) u32x4;

constexpr int NIN    = 16 * 64 * 64 * 256;  // 2^24 elements
constexpr int NBIN   = 512;                 // regions per batch
constexpr int REGION = 8192;                // floats per region (32 KB)
constexpr int RPB    = 16384;               // records per K1 block
constexpr int NBLK1  = NIN / RPB;           // 1024
constexpr int TPB1   = 512;
constexpr int SRCB   = (1 << 20) / RPB;     // 64 source blocks per batch
constexpr int TPB2   = 512;
constexpr int RPBLK2 = 4;                   // regions per K2 block
constexpr int NBLK2  = 16 * NBIN / RPBLK2;  // 2048

// ---------------- K1: single-pass block-local counting sort ----------------
__global__ __launch_bounds__(TPB1, 4) void bin_sort(
    const f32x4* __restrict__ upd, const i32x4* __restrict__ msk,
    u32* __restrict__ recs, u32* __restrict__ packed)
{
    __shared__ int hist[NBIN];
    __shared__ int cursor[NBIN];
    __shared__ int wavesum[8];
    __shared__ u32 staged[RPB];             // 64 KB

    const int tid  = threadIdx.x;
    const int lane = tid & 63;
    const int wv   = tid >> 6;              // 0..7
    const int blk  = blockIdx.x;
    const int v0   = blk * (RPB / 4);

    hist[tid] = 0;                          // NBIN == TPB1
    __syncthreads();

    // load once (NT), pack into registers, histogram
    u32 pk[32]; int bin[32];
#pragma unroll
    for (int j = 0; j < 8; ++j) {
        const int t = v0 + tid + j * TPB1;
        i32x4 m = __builtin_nontemporal_load(&msk[t]);
        f32x4 u = __builtin_nontemporal_load(&upd[t]);
        const int c = (t << 2) & 255;
        {
            const u32 d = (u32)((m.x & ~255) | c);
            bin[j*4+0] = (int)(d >> 13);
            pk[j*4+0] = ((d & 8191) << 19) | ((__float_as_uint(u.x) + 0x1000) >> 13);
        }
        {
            const u32 d = (u32)((m.y & ~255) | (c + 1));
            bin[j*4+1] = (int)(d >> 13);
            pk[j*4+1] = ((d & 8191) << 19) | ((__float_as_uint(u.y) + 0x1000) >> 13);
        }
        {
            const u32 d = (u32)((m.z & ~255) | (c + 2));
            bin[j*4+2] = (int)(d >> 13);
            pk[j*4+2] = ((d & 8191) << 19) | ((__float_as_uint(u.z) + 0x1000) >> 13);
        }
        {
            const u32 d = (u32)((m.w & ~255) | (c + 3));
            bin[j*4+3] = (int)(d >> 13);
            pk[j*4+3] = ((d & 8191) << 19) | ((__float_as_uint(u.w) + 0x1000) >> 13);
        }
#pragma unroll
        for (int e = 0; e < 4; ++e)
            atomicAdd(&hist[bin[j*4+e]], 1);
    }
    __syncthreads();

    // exclusive prefix over 512 bins: 1 bin/thread, wave-shuffle scan
    const int h = hist[tid];
    int s = h;
#pragma unroll
    for (int d = 1; d < 64; d <<= 1) {
        const int v = __shfl_up(s, d, 64);
        if (lane >= d) s += v;
    }
    if (lane == 63) wavesum[wv] = s;
    __syncthreads();
    int woff = 0;
    for (int k = 0; k < wv; ++k) woff += wavesum[k];
    const int excl = woff + s - h;
    cursor[tid] = excl;
    // block-major table: coalesced 2 KB store (K2's strided read is L2-hot)
    packed[(size_t)blk * NBIN + tid] = ((u32)excl << 16) | (u32)h;
    __syncthreads();

    // scatter from registers into staged, sorted by region
#pragma unroll
    for (int k = 0; k < 32; ++k)
        staged[atomicAdd(&cursor[bin[k]], 1)] = pk[k];
    __syncthreads();

    // coalesced copy staged -> global segment (blk * 64 KB)
    u32x4* sg = (u32x4*)staged;
    u32x4* gg = (u32x4*)(recs + (size_t)blk * RPB);
#pragma unroll
    for (int j = 0; j < RPB / 4 / TPB1; ++j)
        gg[tid + j * TPB1] = sg[tid + j * TPB1];
}

// ------- K2: 4 regions per block, cross-region pipelined gather -------
__global__ __launch_bounds__(TPB2, 8) void accumulate(
    const u32* __restrict__ recs, const u32* __restrict__ packed,
    float* __restrict__ out)
{
    __shared__ float region[REGION];        // 32 KB

    const int tid  = threadIdx.x;
    const int lane = tid & 63;
    const int wv   = tid >> 6;              // 0..7
    // XCD-bijective swizzle over 2048 blocks: XCD x owns a contiguous
    // range of region-groups.
    const int lid = ((blockIdx.x & 7) << 8) | (blockIdx.x >> 3);
    const int g0 = lid * RPBLK2;            // first region index (0..8191)
    const int b  = g0 >> 9;                 // batch (RPBLK2 | 512)
    const int r0 = g0 & (NBIN - 1);

    // prologue: table + gather for region r0
    u32 meta[8], rec[8];
    {
        const u32 pl = packed[(size_t)(b * SRCB + lane) * NBIN + r0];
#pragma unroll
        for (int j = 0; j < 8; ++j) {
            const int k = (wv << 3) | j;
            const u32 pj = __shfl(pl, k, 64);
            meta[j] = pj;
            const u32 idx = (u32)((b * SRCB + k) * RPB) + (pj >> 16);
            rec[j] = recs[idx + (lane < (int)(pj & 0xFFFF) ? lane : 0)];
        }
    }

    f32x4* rv = (f32x4*)region;
    for (int i = 0; i < RPBLK2; ++i) {
        // zero LDS region
#pragma unroll
        for (int j = 0; j < REGION / 4 / TPB2; ++j)
            rv[tid + j * TPB2] = f32x4{0.f, 0.f, 0.f, 0.f};
        // prefetch next region's table entry (no LDS dependency)
        u32 pl_next = 0;
        if (i + 1 < RPBLK2)
            pl_next = packed[(size_t)(b * SRCB + lane) * NBIN + (r0 + i + 1)];
        __syncthreads();                    // zero visible

        // atomics for current region (rec/meta loaded last iteration)
#pragma unroll
        for (int j = 0; j < 8; ++j)
            if (lane < (int)(meta[j] & 0xFFFF))
                atomicAdd(&region[rec[j] >> 19],
                          __uint_as_float((rec[j] & 0x7FFFF) << 13));
        // rare tails (cnt > 64; mean 32)
#pragma unroll
        for (int j = 0; j < 8; ++j) {
            const int cnt = (int)(meta[j] & 0xFFFF);
            if (cnt > 64) {
                const int k = (wv << 3) | j;
                const u32 idx = (u32)((b * SRCB + k) * RPB) + (meta[j] >> 16);
                for (int t2 = 64 + lane; t2 < cnt; t2 += 64) {
                    const u32 p = recs[idx + t2];
                    atomicAdd(&region[p >> 19],
                              __uint_as_float((p & 0x7FFFF) << 13));
                }
            }
        }
        // issue next region's gathers (hidden under barrier + writeout)
        if (i + 1 < RPBLK2) {
#pragma unroll
            for (int j = 0; j < 8; ++j) {
                const int k = (wv << 3) | j;
                const u32 pj = __shfl(pl_next, k, 64);
                meta[j] = pj;
                const u32 idx = (u32)((b * SRCB + k) * RPB) + (pj >> 16);
                rec[j] = recs[idx + (lane < (int)(pj & 0xFFFF) ? lane : 0)];
            }
        }
        __syncthreads();                    // atomics done

        // nontemporal write-out (output never re-read)
        f32x4* og = (f32x4*)(out + ((size_t)b << 22) + ((size_t)(r0 + i) << 13));
#pragma unroll
        for (int j = 0; j < REGION / 4 / TPB2; ++j)
            __builtin_nontemporal_store(rv[tid + j * TPB2], &og[tid + j * TPB2]);
        __syncthreads();                    // LDS safe to re-zero
    }
}

// ---------------- fallback (ws too small): R1 atomic scatter ----------------
__global__ __launch_bounds__(256) void unpool_scatter(
    const f32x4* __restrict__ upd, const i32x4* __restrict__ msk,
    float* __restrict__ out)
{
    const int t = blockIdx.x * 256 + threadIdx.x;
    const int e = t << 2;
    f32x4 u = upd[t];
    i32x4 m = msk[t];
    const int b = e >> 20;
    const int c = e & 255;
    float* ob = out + ((long long)b << 22);
    atomicAdd(ob + ((m.x & ~255) | (c    )), u.x);
    atomicAdd(ob + ((m.y & ~255) | (c + 1)), u.y);
    atomicAdd(ob + ((m.z & ~255) | (c + 2)), u.z);
    atomicAdd(ob + ((m.w & ~255) | (c + 3)), u.w);
}

extern "C" void kernel_launch(void* const* d_in, const int* in_sizes, int n_in,
                              void* d_out, int out_size, void* d_ws, size_t ws_size,
                              hipStream_t stream) {
    const f32x4* upd = (const f32x4*)d_in[0];
    const i32x4* msk = (const i32x4*)d_in[1];
    float* out = (float*)d_out;

    constexpr size_t REC_BYTES = (size_t)NIN * 4;                    // 64 MiB
    constexpr size_t PCK_BYTES = (size_t)NBLK1 * NBIN * sizeof(u32); // 2 MiB

    if (ws_size >= REC_BYTES + PCK_BYTES + 4) {      // +4: guarded overread
        u32* recs = (u32*)d_ws;
        u32* packed = (u32*)((char*)d_ws + REC_BYTES);
        bin_sort<<<NBLK1, TPB1, 0, stream>>>(upd, msk, recs, packed);
        accumulate<<<NBLK2, TPB2, 0, stream>>>(recs, packed, out);
    } else {
        (void)hipMemsetAsync(out, 0, (size_t)out_size * sizeof(float), stream);
        unpool_scatter<<<NIN / 4 / 256, 256, 0, stream>>>(upd, msk, out);
    }
}